// Round 8
// baseline (129.461 us; speedup 1.0000x reference)
//
#include <hip/hip_runtime.h>
#include <hip/hip_bf16.h>
#include <cstddef>

// x: (8,64,128,128) fp32 | w1:(64,64,1,1) | b1:(64,) | w2:(9,64,5,5)
// tc1:(16,64,1,1) | tc2:(64,16,1,1) | out:(8,64,128,128) fp32
//
// Pipeline (3 launches):
//   xpack: x -> xbf (bf16, channel-last [b][132][132][64], 2-px zero border,
//          chunk swizzle baked) + per-(b,row) channel sums -> part_rows.
//          EXTRA grid columns carry the weight prep (Weff hi-only bf16
//          A-fragments + betaG) in the shadow of the HBM-bound x pass.
//   prep2: 1 block: reduce part_rows -> xcon, consensus MLP -> ltg[64].
//   fused: TWO vertically-adjacent 8x16 tiles per block, double-buffered
//          halo DMA (t1 = 8 fresh rows only; 4 rows shared with t0's buf).
//          512 blocks x 4 waves, LDS 60.4KB -> 2 blocks/CU (all resident).
//          Schedule: DMA(t0); sync; issue DMA(t1); compute t0 (t1 lands
//          under MFMA+blur); sync; compute t1. Hi-only MFMA conv,
//          raw-logit exchange, Taylor-factored softmax-blur (float2 pk).

#define B 8
#define C 64
#define HW 128
#define NK 9
#define NT 25
#define XR 132          // padded xbf row/col count (128 + 2*2 border)
#define TI 8            // tile rows
#define TJ 16           // tile cols (fixed by MFMA n-dim)
#define HR 12           // halo rows  (TI + 4)
#define HC 20           // halo cols  (TJ + 4)

typedef __attribute__((ext_vector_type(8))) short short8;    // 8 bf16
typedef __attribute__((ext_vector_type(4))) float float4v;   // 4 fp32 acc
typedef __attribute__((ext_vector_type(2))) float float2v;   // packed fp32
typedef __attribute__((ext_vector_type(4))) unsigned int uint4v;

__device__ __forceinline__ unsigned short f2bf(float f) {
    unsigned int u = __float_as_uint(f);
    unsigned int r = u + 0x7FFF + ((u >> 16) & 1);   // RNE
    return (unsigned short)(r >> 16);
}
__device__ __forceinline__ float fast_rcp(float x) {
    float r;
    asm("v_rcp_f32 %0, %1" : "=v"(r) : "v"(x));
    return r;
}
__device__ __forceinline__ void load_lds16(const unsigned short* g, unsigned short* l) {
    __builtin_amdgcn_global_load_lds(
        (const __attribute__((address_space(1))) unsigned int*)g,
        (__attribute__((address_space(3))) unsigned int*)l,
        16, 0, 0);
}

// ---------- kernel 1: x -> xbf + row sums; extra blocks: weight prep ----------
// grid (XR+7, B). blockIdx.x < XR: row r of batch b.
// blockIdx.x >= XR: id = (bx-XR)*B + by; id<50: Weff GEMV chunk (hi-only);
// id==50: betaG; id>50: idle.
__global__ __launch_bounds__(256) void xpack_kernel(const float* __restrict__ x,
                                                    const float* __restrict__ w1,
                                                    const float* __restrict__ b1,
                                                    const float* __restrict__ w2,
                                                    unsigned short* __restrict__ xbf,
                                                    float* __restrict__ part_rows,
                                                    unsigned short* __restrict__ Abuf,
                                                    float* __restrict__ betaG) {
    __shared__ float sw2[NK * 64];    // weight path: w2[m][cc][t] for fixed t
    __shared__ float sw1[64 * 32];    // weight path: w1[cc][ch*32 + j]
    __shared__ float beta_s[NT * NK];
    const int t = threadIdx.x;
    if (blockIdx.x >= XR) {
        const int id = (blockIdx.x - XR) * B + blockIdx.y;
        if (id < 50) {
            const int chunk = id;
            const int tt = chunk >> 1, ch = chunk & 1;
            for (int idx = t; idx < NK * 64; idx += 256) {
                const int m = idx >> 6, cc = idx & 63;
                sw2[idx] = w2[(m * 64 + cc) * NT + tt];
            }
            for (int idx = t; idx < 2048; idx += 256) {
                const int cc = idx >> 5, j = idx & 31;
                sw1[idx] = w1[cc * 64 + ch * 32 + j];
            }
            __syncthreads();
            for (int sidx = 0; sidx < 2; ++sidx) {
                const int slot = sidx * 256 + t;   // (quad*16+m)*8+jj
                const int quad = slot >> 7, m = (slot >> 3) & 15, jj = slot & 7;
                unsigned short hi = 0;
                if (m < NK) {
                    float s = 0.f;
                    for (int cc = 0; cc < 64; ++cc)
                        s += sw2[m * 64 + cc] * sw1[cc * 32 + quad * 8 + jj];
                    hi = f2bf(s);
                }
                Abuf[chunk * 512 + slot] = hi;
            }
        } else if (id == 50) {
            if (t < NT * NK) {
                const int tt = t / NK, k = t - tt * NK;
                float s = 0.f;
                for (int cc = 0; cc < 64; ++cc)
                    s += w2[(k * 64 + cc) * NT + tt] * b1[cc];
                beta_s[t] = s;
            }
            __syncthreads();
            if (t < 225) {   // (ic,jc,k) border classes
                const int ic = t / 45, jc = (t / 9) % 5, k = t % 9;
                float s = 0.f;
                for (int eh = 0; eh < 5; ++eh) {
                    bool rok = (ic == 0) ? (eh >= 2) : (ic == 1) ? (eh >= 1)
                              : (ic == 3) ? (eh <= 3) : (ic == 4) ? (eh <= 2) : true;
                    if (!rok) continue;
                    for (int ew = 0; ew < 5; ++ew) {
                        bool cok = (jc == 0) ? (ew >= 2) : (jc == 1) ? (ew >= 1)
                                  : (jc == 3) ? (ew <= 3) : (jc == 4) ? (ew <= 2) : true;
                        if (cok) s += beta_s[(eh * 5 + ew) * NK + k];
                    }
                }
                betaG[t] = s;
            }
        }
        return;
    }
    const int r = blockIdx.x, b = blockIdx.y;
    unsigned short* rowp = xbf + ((size_t)(b * XR + r)) * (XR * 64);
    if (r < 2 || r >= 130) {             // full zero row: 132*128B = 1056 chunks
        const uint4v z = {0u, 0u, 0u, 0u};
        for (int idx = t; idx < 1056; idx += 256)
            *(uint4v*)(rowp + idx * 8) = z;
        return;
    }
    const int h = r - 2;
    if (t < 32) {                        // zero border cols 0,1,130,131 (8 chunks each)
        const uint4v z = {0u, 0u, 0u, 0u};
        const int q4 = t & 3;
        const int wc = (q4 < 2) ? q4 : (q4 + 128);
        *(uint4v*)(rowp + wc * 64 + ((t >> 2) << 3)) = z;
    }
    const int c8 = t >> 5;               // channel chunk 0..7 (8 ch each)
    const int wl = t & 31;
    const float* xp = x + (((size_t)(b * C + c8 * 8)) * HW + h) * HW;
    float s8[8] = {0.f, 0.f, 0.f, 0.f, 0.f, 0.f, 0.f, 0.f};
#pragma unroll
    for (int k = 0; k < 4; ++k) {
        const int gw = wl + 32 * k;      // 0..127
        const int wc = gw + 2;
        uint4v dv;
#pragma unroll
        for (int j = 0; j < 4; ++j) {
            const float v0 = xp[(size_t)(2 * j) * (HW * HW) + gw];
            const float v1 = xp[(size_t)(2 * j + 1) * (HW * HW) + gw];
            s8[2 * j] += v0;
            s8[2 * j + 1] += v1;
            dv[j] = (unsigned int)f2bf(v0) | ((unsigned int)f2bf(v1) << 16);
        }
        const int sw = ((r & 1) * 4 + wc) & 7;   // == fused-kernel px&7
        *(uint4v*)(rowp + wc * 64 + ((c8 ^ sw) << 3)) = dv;
    }
    // reduce s8 over the 32 threads sharing c8 (lanes are 32-aligned groups)
#pragma unroll
    for (int off = 16; off > 0; off >>= 1) {
#pragma unroll
        for (int j = 0; j < 8; ++j) s8[j] += __shfl_down(s8[j], off);
    }
    if (wl == 0) {
        float* pr = part_rows + ((size_t)(b * HW + h)) * 64 + c8 * 8;
#pragma unroll
        for (int j = 0; j < 8; ++j) pr[j] = s8[j];
    }
}

// ---------- kernel 2: single block: part_rows reduce + consensus MLP -> ltg ----------
__global__ __launch_bounds__(256) void prep2_kernel(const float* __restrict__ part_rows,
                                                    const float* __restrict__ tc1,
                                                    const float* __restrict__ tc2,
                                                    float* __restrict__ ltg) {
    __shared__ float pl[256];
    const int c = threadIdx.x >> 2, seg = threadIdx.x & 3;
    const float* pr = part_rows + (size_t)(seg * 256) * 64 + c;
    float s0 = 0.f, s1 = 0.f, s2 = 0.f, s3 = 0.f;
#pragma unroll 4
    for (int i = 0; i < 256; i += 4) {
        s0 += pr[(size_t)(i + 0) * 64];
        s1 += pr[(size_t)(i + 1) * 64];
        s2 += pr[(size_t)(i + 2) * 64];
        s3 += pr[(size_t)(i + 3) * 64];
    }
    pl[threadIdx.x] = (s0 + s1) + (s2 + s3);
    __syncthreads();
    if (threadIdx.x < 64) {
        const int lane = threadIdx.x;
        float xcv = (pl[lane * 4 + 0] + pl[lane * 4 + 1]
                   + pl[lane * 4 + 2] + pl[lane * 4 + 3]) * (1.f / (B * HW * HW));
        float hh = 0.f;
        for (int c2 = 0; c2 < C; ++c2) {
            float xcc = __shfl(xcv, c2);
            if (lane < 16) hh += tc1[lane * C + c2] * xcc;
        }
        hh = fmaxf(hh, 0.f);
        float ltv = 0.f;
#pragma unroll
        for (int o = 0; o < 16; ++o) {
            float ho = __shfl(hh, o);
            ltv += tc2[lane * 16 + o] * ho;
        }
        ltg[lane] = fmaxf(ltv, 0.f);    // natural-units tmp[c]
    }
}

// ---------- kernel 3: fused, 2 vertically-adjacent 8x16 tiles per block ----------
// 256 thr = 4 waves; wave w: half h=w&1, rowg=w>>1 (tile rows rowg*4..+3).
// LDS: stag0 240px + stag1 160px (x128B) + wpA/wpB = 60.4 KB, 2 blocks/CU,
// 512 blocks -> ALL resident. t1's halo rows 0..3 live in stag0 rows 8..11
// (swizzle identity (px&7)==(4*hr+col)&7 is invariant under the rebasing).
// DMA(t1) issued right after the t0 barrier -> lands under t0's MFMA+blur.
__global__ __launch_bounds__(256, 2) void fused_kernel(const unsigned short* __restrict__ xbf,
                                                       const unsigned short* __restrict__ Abuf,
                                                       const float* __restrict__ betaG,
                                                       const float* __restrict__ ltg,
                                                       float* __restrict__ out) {
    __shared__ __align__(16) unsigned short stag0[HR * HC * 64];  // 30720 B
    __shared__ __align__(16) unsigned short stag1[8 * HC * 64];   // 20480 B
    __shared__ float wpA[NK * 128];               // h=0 half + gated bias
    __shared__ float wpB[NK * 128];               // h=1 half
    const int b = blockIdx.y;
    const int bx = blockIdx.x;                    // 0..63
    const int i0 = (bx >> 3) * 16, j0 = (bx & 7) * TJ;   // tile pair base
    const int tid = threadIdx.x, lane = tid & 63, wid = tid >> 6;
    const int n = lane & 15, q = lane >> 4;
    const int rowg = wid >> 1, h = wid & 1;

    // ---- DMA t0: 12x20 halo (1920 chunks) into stag0 ----
    {
        const unsigned short* xrow0 = xbf + (((size_t)(b * XR + i0)) * XR + j0) * 64;
#pragma unroll
        for (int k = 0; k < 7; ++k) {
            const int ci = k * 256 + tid;
            const int li = ((ci >> 5) * 205) >> 10;   // ci/160, exact for ci<3200
            const int rem = ci - li * 160;
            load_lds16(xrow0 + li * (XR * 64) + rem * 8, stag0 + ci * 8);
        }
        if (tid < 128) {
            const int ci = 1792 + tid;
            const int li = ((ci >> 5) * 205) >> 10;
            const int rem = ci - li * 160;
            load_lds16(xrow0 + li * (XR * 64) + rem * 8, stag0 + ci * 8);
        }
    }
    __syncthreads();   // t0 staged (drains this wave's DMA + barrier)

    // ---- DMA t1: 8 fresh rows (padded rows i0+12..i0+19, 1280 chunks) ----
    {
        const unsigned short* xrow1 = xbf + (((size_t)(b * XR + i0 + 12)) * XR + j0) * 64;
#pragma unroll
        for (int k = 0; k < 5; ++k) {
            const int ci = k * 256 + tid;
            const int li = ((ci >> 5) * 205) >> 10;
            const int rem = ci - li * 160;
            load_lds16(xrow1 + li * (XR * 64) + rem * 8, stag1 + ci * 8);
        }
    }

    const unsigned short* Ab = Abuf + h * 512 + lane * 8;
    const int chs = (h << 2) | q;        // channel-chunk select (pre-swizzle)
    const int rb = rowg * 4;

#pragma unroll
    for (int tt = 0; tt < 2; ++tt) {
        if (tt == 1) __syncthreads();    // t1 staged + wp reads of t0 done
        const int i0t = i0 + tt * 8;

        // ---- gated bias for this wave-half's post-exchange pixel ----
        const int prow = rb + q;
        const int pgi = i0t + prow, pgj = j0 + n;
        float bgv[NK];
        if (h == 0) {
            const int ic = pgi < 2 ? pgi : (pgi > 125 ? pgi - 123 : 2);
            const int jc = pgj < 2 ? pgj : (pgj > 125 ? pgj - 123 : 2);
            const float* bp = betaG + (ic * 5 + jc) * NK;
#pragma unroll
            for (int k = 0; k < NK; ++k) bgv[k] = bp[k];
        }

        // ---- MFMA conv (hi-only), sliding 8-row window per ew column ----
        float4v acc[4];
        const float4v zero4 = {0.f, 0.f, 0.f, 0.f};
#pragma unroll
        for (int g = 0; g < 4; ++g) acc[g] = zero4;
#pragma unroll
        for (int ew = 0; ew < 5; ++ew) {
            short8 w8[8];   // halo rows rb..rb+7 (tile frame) at column ew+n
#pragma unroll
            for (int rr = 0; rr < 8; ++rr) {
                const int hrow = rb + rr;                 // 0..11 tile frame
                const unsigned short* sb2;
                int lr;
                if (tt == 0) { sb2 = stag0; lr = hrow; }
                else if (hrow < 4) { sb2 = stag0; lr = hrow + 8; }
                else { sb2 = stag1; lr = hrow - 4; }
                const int px = lr * HC + ew + n;
                w8[rr] = *(const short8*)(sb2 + px * 64 + ((chs ^ (px & 7)) << 3));
            }
#pragma unroll
            for (int eh = 0; eh < 5; ++eh) {
                const int t = eh * 5 + ew;
                const short8 ahi = *(const short8*)(Ab + t * 1024);
#pragma unroll
                for (int g = 0; g < 4; ++g)
                    acc[g] = __builtin_amdgcn_mfma_f32_16x16x32_bf16(ahi, w8[g + eh], acc[g], 0, 0, 0);
            }
        }

        // ---- intra-wave exchange: lane -> partial logits of its own pixel ----
        float wv[NK];
#pragma unroll
        for (int k = 0; k < NK; ++k) {
            const int src = (k >> 2) * 16 + n;
            const int rr = k & 3;
            float v0 = __shfl(acc[0][rr], src);
            float v1 = __shfl(acc[1][rr], src);
            float v2 = __shfl(acc[2][rr], src);
            float v3 = __shfl(acc[3][rr], src);
            wv[k] = (q == 0) ? v0 : (q == 1) ? v1 : (q == 2) ? v2 : v3;
        }

        // ---- publish raw logit parts ([k][px]: conflict-free) ----
        const int slot = rowg * 64 + lane;   // tile pixel index 0..127
        if (h == 0) {
#pragma unroll
            for (int k = 0; k < NK; ++k) wpA[k * 128 + slot] = wv[k] + bgv[k];
        } else {
#pragma unroll
            for (int k = 0; k < NK; ++k) wpB[k * 128 + slot] = wv[k];
        }
        __syncthreads();   // logits ready

        // ---- blur: 128 px x 8 octets; thread does 2 px x 2 octs ----
#pragma unroll
        for (int sp = 0; sp < 2; ++sp) {
            const int lpx = lane + (sp << 6);            // 0..127
            const int brow = lpx >> 4, bcol = lpx & 15;
            const int bgi = i0t + brow, bgj = j0 + bcol;
            float2v dvp[NK], dv2p[NK];
            float ps1 = 0.f, ps2 = 0.f;
#pragma unroll
            for (int k = 0; k < NK; ++k) {
                const float d = wpA[k * 128 + lpx] + wpB[k * 128 + lpx];
                const float d2 = d * d;
                ps1 += d; ps2 += d2;
                dvp[k][0] = d;  dvp[k][1] = d;
                dv2p[k][0] = d2; dv2p[k][1] = d2;
            }
            float2v ps1p; ps1p[0] = ps1; ps1p[1] = ps1;
            float2v ps2p; ps2p[0] = ps2; ps2p[1] = ps2;
            const float2v ninep = {9.0f, 9.0f};
            int r0 = bgi - 1; r0 = r0 < 0 ? 1 : r0;
            int r2 = bgi + 1; r2 = r2 > 127 ? 126 : r2;
            int c0 = bgj - 1; c0 = c0 < 0 ? 1 : c0;
            int c2 = bgj + 1; c2 = c2 > 127 ? 126 : c2;
            const int R[3] = {r0 - i0t + 2, bgi - i0t + 2, r2 - i0t + 2};
            const int Cc[3] = {c0 - j0 + 2, bgj - j0 + 2, c2 - j0 + 2};
#pragma unroll
            for (int oc = 0; oc < 2; ++oc) {
                const int oct = wid * 2 + oc;            // block covers octs 0..7
                uint4v xs[NK];
#pragma unroll
                for (int kh = 0; kh < 3; ++kh)
#pragma unroll
                    for (int kw = 0; kw < 3; ++kw) {
                        const int hrk = R[kh];           // 0..11 tile frame
                        const unsigned short* sb2;
                        int lr;
                        if (tt == 0) { sb2 = stag0; lr = hrk; }
                        else if (hrk < 4) { sb2 = stag0; lr = hrk + 8; }
                        else { sb2 = stag1; lr = hrk - 4; }
                        const int prc = lr * HC + Cc[kw];
                        xs[kh * 3 + kw] = *(const uint4v*)(sb2 + prc * 64 + ((oct ^ (prc & 7)) << 3));
                    }
                float* outp = out + (((size_t)b * C + oct * 8) * HW + bgi) * HW + bgj;
#pragma unroll
                for (int jj = 0; jj < 4; ++jj) {
                    const float2v tp = *(const float2v*)(ltg + oct * 8 + jj * 2);  // wave-uniform
                    const float2v tph = tp * 0.5f;
                    float2v a0 = {0.f, 0.f}, a1 = {0.f, 0.f}, a2 = {0.f, 0.f};
#pragma unroll
                    for (int k = 0; k < NK; ++k) {
                        const unsigned int u = xs[k][jj];
                        float2v xv;
                        xv[0] = __uint_as_float(u << 16);
                        xv[1] = __uint_as_float(u & 0xffff0000u);
                        a0 += xv;
                        a1 = __builtin_elementwise_fma(dvp[k], xv, a1);
                        a2 = __builtin_elementwise_fma(dv2p[k], xv, a2);
                    }
                    const float2v nump = __builtin_elementwise_fma(
                        tp, __builtin_elementwise_fma(tph, a2, a1), a0);
                    const float2v denp = __builtin_elementwise_fma(
                        tp, __builtin_elementwise_fma(tph, ps2p, ps1p), ninep);
                    outp[(size_t)(jj * 2) * (HW * HW)] = nump[0] * fast_rcp(denp[0]);
                    outp[(size_t)(jj * 2 + 1) * (HW * HW)] = nump[1] * fast_rcp(denp[1]);
                }
            }
        }
    }
}

extern "C" void kernel_launch(void* const* d_in, const int* in_sizes, int n_in,
                              void* d_out, int out_size, void* d_ws, size_t ws_size,
                              hipStream_t stream) {
    const float* x   = (const float*)d_in[0];
    const float* w1  = (const float*)d_in[1];
    const float* b1  = (const float*)d_in[2];
    const float* w2  = (const float*)d_in[3];
    const float* tc1 = (const float*)d_in[4];
    const float* tc2 = (const float*)d_in[5];
    float* out = (float*)d_out;

    // workspace layout (bytes)
    char* ws = (char*)d_ws;
    float* ltg   = (float*)(ws + 0);                         // 64 fl
    unsigned short* Abuf = (unsigned short*)(ws + 1024);     // 25600 ush = 51200 B
    float* betaG = (float*)(ws + 53248);                     // 225 fl
    float* part_rows = (float*)(ws + 54272);                 // 1024*64 fl = 262144 B
    unsigned short* xbf  = (unsigned short*)(ws + 316416);   // 8*132*132*64 ush = 17.8 MB

    xpack_kernel<<<dim3(XR + 7, B), 256, 0, stream>>>(x, w1, b1, w2, xbf, part_rows, Abuf, betaG);
    prep2_kernel<<<1, 256, 0, stream>>>(part_rows, tc1, tc2, ltg);
    fused_kernel<<<dim3(64, B), 256, 0, stream>>>(xbf, Abuf, betaG, ltg, out);
}

// Round 9
// 126.838 us; speedup vs baseline: 1.0207x; 1.0207x over previous
//
#include <hip/hip_runtime.h>
#include <hip/hip_bf16.h>
#include <cstddef>

// x: (8,64,128,128) fp32 | w1:(64,64,1,1) | b1:(64,) | w2:(9,64,5,5)
// tc1:(16,64,1,1) | tc2:(64,16,1,1) | out:(8,64,128,128) fp32
//
// Pipeline (3 launches):
//   xpack: x -> xbf (bf16, channel-last [b][132][132][64], 2-px zero border,
//          chunk swizzle baked) + per-(b,row) channel sums -> part_rows.
//          EXTRA grid columns carry the weight prep (Weff hi-only bf16
//          A-fragments + betaG) in the shadow of the HBM-bound x pass.
//   prep2: 1 block: reduce part_rows -> xcon, consensus MLP -> ltg[64].
//   fused: 8x16 tile, 256 thr = 4 waves, 1024 blocks = 4 blocks/CU.
//          Halo DMA'd via global_load_lds dwordx4 (30.7 KB). A-fragments
//          REGISTER-PIPELINED: ew=0's 5 frags prefetched under the DMA
//          drain, each loop phase prefetches ew+1's frags before computing
//          ew (kills the inline global-load stall that capped R4 at 56
//          VGPRs). Hi-only MFMA conv, raw-logit exchange, Taylor-factored
//          softmax-blur (e^u ~= 1+u+u^2/2, |u|<=~0.04) with float2 pk math.

#define B 8
#define C 64
#define HW 128
#define NK 9
#define NT 25
#define XR 132          // padded xbf row/col count (128 + 2*2 border)
#define TI 8            // fused tile rows
#define TJ 16           // fused tile cols (fixed by MFMA n-dim)
#define HR 12           // halo rows  (TI + 4)
#define HC 20           // halo cols  (TJ + 4)

typedef __attribute__((ext_vector_type(8))) short short8;    // 8 bf16
typedef __attribute__((ext_vector_type(4))) float float4v;   // 4 fp32 acc
typedef __attribute__((ext_vector_type(2))) float float2v;   // packed fp32
typedef __attribute__((ext_vector_type(4))) unsigned int uint4v;

__device__ __forceinline__ unsigned short f2bf(float f) {
    unsigned int u = __float_as_uint(f);
    unsigned int r = u + 0x7FFF + ((u >> 16) & 1);   // RNE
    return (unsigned short)(r >> 16);
}
__device__ __forceinline__ float fast_rcp(float x) {
    float r;
    asm("v_rcp_f32 %0, %1" : "=v"(r) : "v"(x));
    return r;
}
__device__ __forceinline__ void load_lds16(const unsigned short* g, unsigned short* l) {
    __builtin_amdgcn_global_load_lds(
        (const __attribute__((address_space(1))) unsigned int*)g,
        (__attribute__((address_space(3))) unsigned int*)l,
        16, 0, 0);
}

// ---------- kernel 1: x -> xbf + row sums; extra blocks: weight prep ----------
// grid (XR+7, B). blockIdx.x < XR: row r of batch b.
// blockIdx.x >= XR: id = (bx-XR)*B + by; id<50: Weff GEMV chunk (hi-only);
// id==50: betaG; id>50: idle.
__global__ __launch_bounds__(256) void xpack_kernel(const float* __restrict__ x,
                                                    const float* __restrict__ w1,
                                                    const float* __restrict__ b1,
                                                    const float* __restrict__ w2,
                                                    unsigned short* __restrict__ xbf,
                                                    float* __restrict__ part_rows,
                                                    unsigned short* __restrict__ Abuf,
                                                    float* __restrict__ betaG) {
    __shared__ float sw2[NK * 64];    // weight path: w2[m][cc][t] for fixed t
    __shared__ float sw1[64 * 32];    // weight path: w1[cc][ch*32 + j]
    __shared__ float beta_s[NT * NK];
    const int t = threadIdx.x;
    if (blockIdx.x >= XR) {
        const int id = (blockIdx.x - XR) * B + blockIdx.y;
        if (id < 50) {
            const int chunk = id;
            const int tt = chunk >> 1, ch = chunk & 1;
            for (int idx = t; idx < NK * 64; idx += 256) {
                const int m = idx >> 6, cc = idx & 63;
                sw2[idx] = w2[(m * 64 + cc) * NT + tt];
            }
            for (int idx = t; idx < 2048; idx += 256) {
                const int cc = idx >> 5, j = idx & 31;
                sw1[idx] = w1[cc * 64 + ch * 32 + j];
            }
            __syncthreads();
            for (int sidx = 0; sidx < 2; ++sidx) {
                const int slot = sidx * 256 + t;   // (quad*16+m)*8+jj
                const int quad = slot >> 7, m = (slot >> 3) & 15, jj = slot & 7;
                unsigned short hi = 0;
                if (m < NK) {
                    float s = 0.f;
                    for (int cc = 0; cc < 64; ++cc)
                        s += sw2[m * 64 + cc] * sw1[cc * 32 + quad * 8 + jj];
                    hi = f2bf(s);
                }
                Abuf[chunk * 512 + slot] = hi;
            }
        } else if (id == 50) {
            if (t < NT * NK) {
                const int tt = t / NK, k = t - tt * NK;
                float s = 0.f;
                for (int cc = 0; cc < 64; ++cc)
                    s += w2[(k * 64 + cc) * NT + tt] * b1[cc];
                beta_s[t] = s;
            }
            __syncthreads();
            if (t < 225) {   // (ic,jc,k) border classes
                const int ic = t / 45, jc = (t / 9) % 5, k = t % 9;
                float s = 0.f;
                for (int eh = 0; eh < 5; ++eh) {
                    bool rok = (ic == 0) ? (eh >= 2) : (ic == 1) ? (eh >= 1)
                              : (ic == 3) ? (eh <= 3) : (ic == 4) ? (eh <= 2) : true;
                    if (!rok) continue;
                    for (int ew = 0; ew < 5; ++ew) {
                        bool cok = (jc == 0) ? (ew >= 2) : (jc == 1) ? (ew >= 1)
                                  : (jc == 3) ? (ew <= 3) : (jc == 4) ? (ew <= 2) : true;
                        if (cok) s += beta_s[(eh * 5 + ew) * NK + k];
                    }
                }
                betaG[t] = s;
            }
        }
        return;
    }
    const int r = blockIdx.x, b = blockIdx.y;
    unsigned short* rowp = xbf + ((size_t)(b * XR + r)) * (XR * 64);
    if (r < 2 || r >= 130) {             // full zero row: 132*128B = 1056 chunks
        const uint4v z = {0u, 0u, 0u, 0u};
        for (int idx = t; idx < 1056; idx += 256)
            *(uint4v*)(rowp + idx * 8) = z;
        return;
    }
    const int h = r - 2;
    if (t < 32) {                        // zero border cols 0,1,130,131 (8 chunks each)
        const uint4v z = {0u, 0u, 0u, 0u};
        const int q4 = t & 3;
        const int wc = (q4 < 2) ? q4 : (q4 + 128);
        *(uint4v*)(rowp + wc * 64 + ((t >> 2) << 3)) = z;
    }
    const int c8 = t >> 5;               // channel chunk 0..7 (8 ch each)
    const int wl = t & 31;
    const float* xp = x + (((size_t)(b * C + c8 * 8)) * HW + h) * HW;
    float s8[8] = {0.f, 0.f, 0.f, 0.f, 0.f, 0.f, 0.f, 0.f};
#pragma unroll
    for (int k = 0; k < 4; ++k) {
        const int gw = wl + 32 * k;      // 0..127
        const int wc = gw + 2;
        uint4v dv;
#pragma unroll
        for (int j = 0; j < 4; ++j) {
            const float v0 = xp[(size_t)(2 * j) * (HW * HW) + gw];
            const float v1 = xp[(size_t)(2 * j + 1) * (HW * HW) + gw];
            s8[2 * j] += v0;
            s8[2 * j + 1] += v1;
            dv[j] = (unsigned int)f2bf(v0) | ((unsigned int)f2bf(v1) << 16);
        }
        const int sw = ((r & 1) * 4 + wc) & 7;   // == fused-kernel px&7
        *(uint4v*)(rowp + wc * 64 + ((c8 ^ sw) << 3)) = dv;
    }
    // reduce s8 over the 32 threads sharing c8 (lanes are 32-aligned groups)
#pragma unroll
    for (int off = 16; off > 0; off >>= 1) {
#pragma unroll
        for (int j = 0; j < 8; ++j) s8[j] += __shfl_down(s8[j], off);
    }
    if (wl == 0) {
        float* pr = part_rows + ((size_t)(b * HW + h)) * 64 + c8 * 8;
#pragma unroll
        for (int j = 0; j < 8; ++j) pr[j] = s8[j];
    }
}

// ---------- kernel 2: single block: part_rows reduce + consensus MLP -> ltg ----------
__global__ __launch_bounds__(256) void prep2_kernel(const float* __restrict__ part_rows,
                                                    const float* __restrict__ tc1,
                                                    const float* __restrict__ tc2,
                                                    float* __restrict__ ltg) {
    __shared__ float pl[256];
    const int c = threadIdx.x >> 2, seg = threadIdx.x & 3;
    const float* pr = part_rows + (size_t)(seg * 256) * 64 + c;
    float s0 = 0.f, s1 = 0.f, s2 = 0.f, s3 = 0.f;
#pragma unroll 4
    for (int i = 0; i < 256; i += 4) {
        s0 += pr[(size_t)(i + 0) * 64];
        s1 += pr[(size_t)(i + 1) * 64];
        s2 += pr[(size_t)(i + 2) * 64];
        s3 += pr[(size_t)(i + 3) * 64];
    }
    pl[threadIdx.x] = (s0 + s1) + (s2 + s3);
    __syncthreads();
    if (threadIdx.x < 64) {
        const int lane = threadIdx.x;
        float xcv = (pl[lane * 4 + 0] + pl[lane * 4 + 1]
                   + pl[lane * 4 + 2] + pl[lane * 4 + 3]) * (1.f / (B * HW * HW));
        float hh = 0.f;
        for (int c2 = 0; c2 < C; ++c2) {
            float xcc = __shfl(xcv, c2);
            if (lane < 16) hh += tc1[lane * C + c2] * xcc;
        }
        hh = fmaxf(hh, 0.f);
        float ltv = 0.f;
#pragma unroll
        for (int o = 0; o < 16; ++o) {
            float ho = __shfl(hh, o);
            ltv += tc2[lane * 16 + o] * ho;
        }
        ltg[lane] = fmaxf(ltv, 0.f);    // natural-units tmp[c]
    }
}

// ---------- kernel 3: fused MFMA conv + Taylor softmax + blur, 8x16 tile ----------
// 256 thr = 4 waves; wave w: half h=w&1, rowg=w>>1 (output rows rowg*4..+3).
// LDS: stag 240px x 128B (30.7 KB) + wpA/wpB 9x128 fl (9.2 KB) = 39.9 KB,
// 4 blocks/CU. A-fragments register-pipelined by ew phase (2x5 short8 =
// 40 VGPRs); ew=0 prefetched before barrier 1 so it drains with the DMA.
__global__ __launch_bounds__(256, 4) void fused_kernel(const unsigned short* __restrict__ xbf,
                                                       const unsigned short* __restrict__ Abuf,
                                                       const float* __restrict__ betaG,
                                                       const float* __restrict__ ltg,
                                                       float* __restrict__ out) {
    __shared__ __align__(16) unsigned short stag[HR * HC * 64];   // 30720 B
    __shared__ float wpA[NK * 128];               // h=0 half + gated bias
    __shared__ float wpB[NK * 128];               // h=1 half
    const int b = blockIdx.y;
    const int i0 = (blockIdx.x >> 3) * TI, j0 = (blockIdx.x & 7) * TJ;
    const int tid = threadIdx.x, lane = tid & 63, wid = tid >> 6;
    const int n = lane & 15, q = lane >> 4;
    const int rowg = wid >> 1, h = wid & 1;

    // ---- stage 12x20 halo x 64 ch bf16 from xbf (linear DMA, 1920 chunks) ----
    {
        const unsigned short* xrow0 = xbf + (((size_t)(b * XR + i0)) * XR + j0) * 64;
#pragma unroll
        for (int k = 0; k < 7; ++k) {
            const int ci = k * 256 + tid;
            const int li = ((ci >> 5) * 205) >> 10;   // ci/160, exact for ci<3200
            const int rem = ci - li * 160;
            load_lds16(xrow0 + li * (XR * 64) + rem * 8, stag + ci * 8);
        }
        if (tid < 128) {                               // tail: 2 full waves
            const int ci = 1792 + tid;
            const int li = ((ci >> 5) * 205) >> 10;
            const int rem = ci - li * 160;
            load_lds16(xrow0 + li * (XR * 64) + rem * 8, stag + ci * 8);
        }
    }

    // ---- even waves: prefetch gated bias for their post-exchange pixel ----
    const int prow = rowg * 4 + q;
    const int pgi = i0 + prow, pgj = j0 + n;
    float bgv[NK];
    if (h == 0) {
        const int ic = pgi < 2 ? pgi : (pgi > 125 ? pgi - 123 : 2);
        const int jc = pgj < 2 ? pgj : (pgj > 125 ? pgj - 123 : 2);
        const float* bp = betaG + (ic * 5 + jc) * NK;
#pragma unroll
        for (int k = 0; k < NK; ++k) bgv[k] = bp[k];
    }

    // ---- prefetch ew=0 A-fragments (rides the DMA drain at barrier 1) ----
    const unsigned short* Ab = Abuf + h * 512 + lane * 8;
    short8 af[2][5];
#pragma unroll
    for (int eh = 0; eh < 5; ++eh)
        af[0][eh] = *(const short8*)(Ab + (eh * 5) * 1024);

    __syncthreads();   // barrier 1: stag DMA + af[0] drained

    // ---- MFMA conv (hi-only), A-frags double-buffered by ew phase ----
    float4v acc[4];
    const float4v zero4 = {0.f, 0.f, 0.f, 0.f};
#pragma unroll
    for (int g = 0; g < 4; ++g) acc[g] = zero4;

    const int chs = (h << 2) | q;        // channel-chunk select (pre-swizzle)
    const int rb = rowg * 4;
#pragma unroll
    for (int ew = 0; ew < 5; ++ew) {
        const int cur = ew & 1, nxt = cur ^ 1;
        if (ew < 4) {                    // prefetch phase ew+1's A-frags
#pragma unroll
            for (int eh = 0; eh < 5; ++eh)
                af[nxt][eh] = *(const short8*)(Ab + (eh * 5 + ew + 1) * 1024);
        }
        short8 w8[8];   // halo rows rb .. rb+7 at column ew+n
#pragma unroll
        for (int rr = 0; rr < 8; ++rr) {
            const int px = (rb + rr) * HC + ew + n;
            w8[rr] = *(const short8*)(stag + px * 64 + ((chs ^ (px & 7)) << 3));
        }
#pragma unroll
        for (int eh = 0; eh < 5; ++eh) {
#pragma unroll
            for (int g = 0; g < 4; ++g)
                acc[g] = __builtin_amdgcn_mfma_f32_16x16x32_bf16(af[cur][eh], w8[g + eh], acc[g], 0, 0, 0);
        }
    }

    // ---- intra-wave exchange: lane -> partial logits of its own pixel ----
    float wv[NK];
#pragma unroll
    for (int k = 0; k < NK; ++k) {
        const int src = (k >> 2) * 16 + n;
        const int rr = k & 3;
        float v0 = __shfl(acc[0][rr], src);
        float v1 = __shfl(acc[1][rr], src);
        float v2 = __shfl(acc[2][rr], src);
        float v3 = __shfl(acc[3][rr], src);
        wv[k] = (q == 0) ? v0 : (q == 1) ? v1 : (q == 2) ? v2 : v3;
    }

    // ---- both halves publish raw logit parts ([k][px]: conflict-free) ----
    const int slot = rowg * 64 + lane;   // local pixel index 0..127
    if (h == 0) {
#pragma unroll
        for (int k = 0; k < NK; ++k) wpA[k * 128 + slot] = wv[k] + bgv[k];
    } else {
#pragma unroll
        for (int k = 0; k < NK; ++k) wpB[k * 128 + slot] = wv[k];
    }
    __syncthreads();   // barrier 2: logits ready

    // ---- blur: 128 px x 8 octets = 1024 tasks; thread does 2 px x 2 octs ----
#pragma unroll
    for (int sp = 0; sp < 2; ++sp) {
        const int lpx = lane + (sp << 6);            // 0..127
        const int brow = lpx >> 4, bcol = lpx & 15;
        const int bgi = i0 + brow, bgj = j0 + bcol;
        float2v dvp[NK], dv2p[NK];
        float ps1 = 0.f, ps2 = 0.f;                  // per-pixel Sum dv, Sum dv^2
#pragma unroll
        for (int k = 0; k < NK; ++k) {
            const float d = wpA[k * 128 + lpx] + wpB[k * 128 + lpx];
            const float d2 = d * d;
            ps1 += d; ps2 += d2;
            dvp[k][0] = d;  dvp[k][1] = d;
            dv2p[k][0] = d2; dv2p[k][1] = d2;
        }
        float2v ps1p; ps1p[0] = ps1; ps1p[1] = ps1;
        float2v ps2p; ps2p[0] = ps2; ps2p[1] = ps2;
        const float2v ninep = {9.0f, 9.0f};
        int r0 = bgi - 1; r0 = r0 < 0 ? 1 : r0;
        int r2 = bgi + 1; r2 = r2 > 127 ? 126 : r2;
        int c0 = bgj - 1; c0 = c0 < 0 ? 1 : c0;
        int c2 = bgj + 1; c2 = c2 > 127 ? 126 : c2;
        const int R[3] = {r0 - i0 + 2, bgi - i0 + 2, r2 - i0 + 2};
        const int Cc[3] = {c0 - j0 + 2, bgj - j0 + 2, c2 - j0 + 2};
#pragma unroll
        for (int oc = 0; oc < 2; ++oc) {
            const int oct = wid * 2 + oc;            // block covers octs 0..7
            uint4v xs[NK];
#pragma unroll
            for (int kh = 0; kh < 3; ++kh)
#pragma unroll
                for (int kw = 0; kw < 3; ++kw) {
                    const int prc = R[kh] * HC + Cc[kw];
                    xs[kh * 3 + kw] = *(const uint4v*)(stag + prc * 64 + ((oct ^ (prc & 7)) << 3));
                }
            float* outp = out + (((size_t)b * C + oct * 8) * HW + bgi) * HW + bgj;
#pragma unroll
            for (int jj = 0; jj < 4; ++jj) {
                const float2v tp = *(const float2v*)(ltg + oct * 8 + jj * 2);  // wave-uniform
                const float2v tph = tp * 0.5f;
                float2v a0 = {0.f, 0.f}, a1 = {0.f, 0.f}, a2 = {0.f, 0.f};
#pragma unroll
                for (int k = 0; k < NK; ++k) {
                    const unsigned int u = xs[k][jj];
                    float2v xv;
                    xv[0] = __uint_as_float(u << 16);
                    xv[1] = __uint_as_float(u & 0xffff0000u);
                    a0 += xv;
                    a1 = __builtin_elementwise_fma(dvp[k], xv, a1);
                    a2 = __builtin_elementwise_fma(dv2p[k], xv, a2);
                }
                const float2v nump = __builtin_elementwise_fma(
                    tp, __builtin_elementwise_fma(tph, a2, a1), a0);
                const float2v denp = __builtin_elementwise_fma(
                    tp, __builtin_elementwise_fma(tph, ps2p, ps1p), ninep);
                outp[(size_t)(jj * 2) * (HW * HW)] = nump[0] * fast_rcp(denp[0]);
                outp[(size_t)(jj * 2 + 1) * (HW * HW)] = nump[1] * fast_rcp(denp[1]);
            }
        }
    }
}

extern "C" void kernel_launch(void* const* d_in, const int* in_sizes, int n_in,
                              void* d_out, int out_size, void* d_ws, size_t ws_size,
                              hipStream_t stream) {
    const float* x   = (const float*)d_in[0];
    const float* w1  = (const float*)d_in[1];
    const float* b1  = (const float*)d_in[2];
    const float* w2  = (const float*)d_in[3];
    const float* tc1 = (const float*)d_in[4];
    const float* tc2 = (const float*)d_in[5];
    float* out = (float*)d_out;

    // workspace layout (bytes)
    char* ws = (char*)d_ws;
    float* ltg   = (float*)(ws + 0);                         // 64 fl
    unsigned short* Abuf = (unsigned short*)(ws + 1024);     // 25600 ush = 51200 B
    float* betaG = (float*)(ws + 53248);                     // 225 fl
    float* part_rows = (float*)(ws + 54272);                 // 1024*64 fl = 262144 B
    unsigned short* xbf  = (unsigned short*)(ws + 316416);   // 8*132*132*64 ush = 17.8 MB

    xpack_kernel<<<dim3(XR + 7, B), 256, 0, stream>>>(x, w1, b1, w2, xbf, part_rows, Abuf, betaG);
    prep2_kernel<<<1, 256, 0, stream>>>(part_rows, tc1, tc2, ltg);
    fused_kernel<<<dim3(128, B), 256, 0, stream>>>(xbf, Abuf, betaG, ltg, out);
}